// Round 1
// baseline (888.025 us; speedup 1.0000x reference)
//
#include <hip/hip_runtime.h>

typedef unsigned short u16;
typedef __attribute__((ext_vector_type(8))) short short8;
typedef __attribute__((ext_vector_type(4))) float f32x4;

constexpr int B_ = 2;
constexpr int H_ = 8;
constexpr int KVH_ = 4;
constexpr int S_ = 2048;
constexpr int D_ = 256;
constexpr int HID_ = 2304;
constexpr int QKVN_ = 4096;   // 2048 q + 1024 k + 1024 v
constexpr int AON_ = 2048;    // H_*D_

__device__ __forceinline__ float b2f(u16 u) {
  union { float f; unsigned int i; } x; x.i = ((unsigned int)u) << 16; return x.f;
}
__device__ __forceinline__ u16 f2b(float f) {
  unsigned int x = __float_as_uint(f);
  unsigned int r = (x + 0x7fffu + ((x >> 16) & 1u)) >> 16;
  return (u16)r;
}

// ---------------- cast fp32 -> bf16 (vectorized) ----------------
__global__ void cast_kernel(const float* __restrict__ in, u16* __restrict__ out) {
  size_t i = ((size_t)blockIdx.x * 256 + threadIdx.x) * 4;
  float4 v = *(const float4*)(in + i);
  unsigned int lo = (unsigned int)f2b(v.x) | ((unsigned int)f2b(v.y) << 16);
  unsigned int hi = (unsigned int)f2b(v.z) | ((unsigned int)f2b(v.w) << 16);
  uint2 o; o.x = lo; o.y = hi;
  *(uint2*)(out + i) = o;
}

// ---------------- transpose + cast: src (R x C) fp32 -> dst (C x R) bf16 ----------------
__global__ void transpose_cast(const float* __restrict__ src, u16* __restrict__ dst,
                               int R, int C) {
  __shared__ float tile[64][65];
  int r0 = blockIdx.y * 64, c0 = blockIdx.x * 64;
  int t = threadIdx.x;
#pragma unroll
  for (int i = 0; i < 16; ++i) {
    int e = i * 256 + t;
    int r = e >> 6, c = e & 63;
    tile[r][c] = src[(size_t)(r0 + r) * C + (c0 + c)];
  }
  __syncthreads();
#pragma unroll
  for (int i = 0; i < 16; ++i) {
    int e = i * 256 + t;
    int orow = e >> 6, ocol = e & 63;
    dst[(size_t)(c0 + orow) * R + (r0 + ocol)] = f2b(tile[ocol][orow]);
  }
}

// ---------------- m97-style bf16 GEMM: C = A(MxK) * B^T where B is (N x K) ----------------
template <int OUTF32>
__global__ __launch_bounds__(256, 2) void gemm_bt(
    const u16* __restrict__ A, const u16* __restrict__ B, void* __restrict__ Cp,
    int M, int N, int K) {
  __shared__ u16 As[128 * 32];
  __shared__ u16 Bs[128 * 32];
  int m0 = blockIdx.y * 128, n0 = blockIdx.x * 128;
  int tid = threadIdx.x;
  int lane = tid & 63, wave = tid >> 6;
  int wy = wave >> 1, wx = wave & 1;
  int quad = lane >> 4, l16 = lane & 15;
  f32x4 acc[4][4] = {};
  for (int k0 = 0; k0 < K; k0 += 32) {
#pragma unroll
    for (int i = 0; i < 2; ++i) {
      int chunk = i * 256 + tid;
      int row = chunk >> 2, col = (chunk & 3) << 3;
      __builtin_amdgcn_global_load_lds(
          (const __attribute__((address_space(1))) void*)(A + (size_t)(m0 + row) * K + k0 + col),
          (__attribute__((address_space(3))) void*)(As + chunk * 8), 16, 0, 0);
    }
#pragma unroll
    for (int i = 0; i < 2; ++i) {
      int chunk = i * 256 + tid;
      int row = chunk >> 2, col = (chunk & 3) << 3;
      __builtin_amdgcn_global_load_lds(
          (const __attribute__((address_space(1))) void*)(B + (size_t)(n0 + row) * K + k0 + col),
          (__attribute__((address_space(3))) void*)(Bs + chunk * 8), 16, 0, 0);
    }
    __syncthreads();
    short8 af[4], bf[4];
#pragma unroll
    for (int mi = 0; mi < 4; ++mi)
      af[mi] = *(const short8*)(As + (wy * 64 + mi * 16 + l16) * 32 + quad * 8);
#pragma unroll
    for (int ni = 0; ni < 4; ++ni)
      bf[ni] = *(const short8*)(Bs + (wx * 64 + ni * 16 + l16) * 32 + quad * 8);
#pragma unroll
    for (int mi = 0; mi < 4; ++mi)
#pragma unroll
      for (int ni = 0; ni < 4; ++ni)
        acc[mi][ni] = __builtin_amdgcn_mfma_f32_16x16x32_bf16(af[mi], bf[ni], acc[mi][ni], 0, 0, 0);
    __syncthreads();
  }
#pragma unroll
  for (int mi = 0; mi < 4; ++mi) {
#pragma unroll
    for (int ni = 0; ni < 4; ++ni) {
#pragma unroll
      for (int r = 0; r < 4; ++r) {
        int row = m0 + wy * 64 + mi * 16 + quad * 4 + r;
        int col = n0 + wx * 64 + ni * 16 + l16;
        if (OUTF32)
          ((float*)Cp)[(size_t)row * N + col] = acc[mi][ni][r];
        else
          ((u16*)Cp)[(size_t)row * N + col] = f2b(acc[mi][ni][r]);
      }
    }
  }
}

// ---------------- RoPE + rearrange: qkv (4096 x 4096) -> Q (B,H,S,D), K (B,KVH,S,D) ----------------
__global__ void rope_kernel(const u16* __restrict__ qkv, const float* __restrict__ cs,
                            const float* __restrict__ sn, u16* __restrict__ Qr,
                            u16* __restrict__ Kr) {
  int row = blockIdx.x;          // b*S + s
  int b = row >> 11, s = row & 2047;
  int d = threadIdx.x;           // 0..255
  const u16* qrow = qkv + (size_t)row * QKVN_;
  float c = cs[(size_t)row * D_ + d];
  float si = sn[(size_t)row * D_ + d];
  int dp = (d < 128) ? d + 128 : d - 128;
  float sgn = (d < 128) ? -1.f : 1.f;
#pragma unroll
  for (int h = 0; h < H_; ++h) {
    float v = b2f(qrow[h * D_ + d]);
    float p = sgn * b2f(qrow[h * D_ + dp]);
    Qr[((size_t)(b * H_ + h) * S_ + s) * D_ + d] = f2b(v * c + p * si);
  }
#pragma unroll
  for (int g = 0; g < KVH_; ++g) {
    float v = b2f(qrow[2048 + g * D_ + d]);
    float p = sgn * b2f(qrow[2048 + g * D_ + dp]);
    Kr[((size_t)(b * KVH_ + g) * S_ + s) * D_ + d] = f2b(v * c + p * si);
  }
}

// ---------------- V transpose: qkv v-part -> Vt (B,KVH,D,S) ----------------
__global__ void transpose_v(const u16* __restrict__ qkv, u16* __restrict__ Vt) {
  __shared__ u16 tile[64][72];
  int d0 = blockIdx.x * 64, s0 = blockIdx.y * 64, g = blockIdx.z; // g = b*KVH+kvh
  int b = g >> 2, kvh = g & 3;
  int t = threadIdx.x;
#pragma unroll
  for (int i = 0; i < 16; ++i) {
    int e = i * 256 + t;
    int r = e >> 6, c = e & 63;
    tile[r][c] = qkv[(size_t)(b * S_ + s0 + r) * QKVN_ + 3072 + kvh * D_ + d0 + c];
  }
  __syncthreads();
#pragma unroll
  for (int i = 0; i < 16; ++i) {
    int e = i * 256 + t;
    int orow = e >> 6, ocol = e & 63;
    Vt[((size_t)g * D_ + d0 + orow) * S_ + s0 + ocol] = tile[ocol][orow];
  }
}

// ---------------- flash attention: causal + softcap, GQA ----------------
__global__ __launch_bounds__(256, 2) void attn_kernel(
    const u16* __restrict__ Qr, const u16* __restrict__ Kr, const u16* __restrict__ Vt,
    u16* __restrict__ Ao) {
  int qt = blockIdx.x, h = blockIdx.y, b = blockIdx.z;
  int kvh = h >> 1;  // N_REP = 2
  int tid = threadIdx.x, wave = tid >> 6, lane = tid & 63;
  int quad = lane >> 4, l16 = lane & 15;
  int q0 = qt * 64;
  // Q fragments in registers: wave owns q rows [q0+wave*16, +16); A-layout m=l16, k=quad*8+j
  const u16* Qbase = Qr + ((size_t)(b * H_ + h) * S_ + q0 + wave * 16 + l16) * D_;
  short8 qf[8];
#pragma unroll
  for (int kk = 0; kk < 8; ++kk)
    qf[kk] = *(const short8*)(Qbase + kk * 32 + quad * 8);
  const u16* Kbase = Kr + (size_t)(b * KVH_ + kvh) * S_ * D_;
  const u16* Vbase = Vt + (size_t)(b * KVH_ + kvh) * D_ * S_;
  float m_r[4], l_r[4];
#pragma unroll
  for (int r = 0; r < 4; ++r) { m_r[r] = -1e30f; l_r[r] = 0.f; }
  f32x4 o_acc[16] = {};
  __shared__ u16 Ps[4][16 * 72];

  for (int kt = 0; kt <= qt; ++kt) {
    int k0 = kt * 64;
    // S = Q K^T : 4 key sub-tiles of 16
    f32x4 sacc[4] = {};
#pragma unroll
    for (int n = 0; n < 4; ++n) {
      const u16* kb = Kbase + (size_t)(k0 + n * 16 + l16) * D_;
#pragma unroll
      for (int kk = 0; kk < 8; ++kk) {
        short8 bfr = *(const short8*)(kb + kk * 32 + quad * 8);
        sacc[n] = __builtin_amdgcn_mfma_f32_16x16x32_bf16(qf[kk], bfr, sacc[n], 0, 0, 0);
      }
    }
    // softcap + causal mask + online softmax
    float e[4][4];
    float tm[4] = {-1e30f, -1e30f, -1e30f, -1e30f};
#pragma unroll
    for (int n = 0; n < 4; ++n) {
      int key = k0 + n * 16 + l16;
#pragma unroll
      for (int r = 0; r < 4; ++r) {
        int qq = q0 + wave * 16 + quad * 4 + r;
        float s = 50.0f * tanhf(sacc[n][r] * (0.0625f / 50.0f));  // SCALE=1/16, cap 50
        s = (key <= qq) ? s : -1e30f;
        e[n][r] = s;
        tm[r] = fmaxf(tm[r], s);
      }
    }
#pragma unroll
    for (int off = 1; off < 16; off <<= 1)
#pragma unroll
      for (int r = 0; r < 4; ++r)
        tm[r] = fmaxf(tm[r], __shfl_xor(tm[r], off, 64));
    float alpha[4], rs[4];
#pragma unroll
    for (int r = 0; r < 4; ++r) {
      float mn = fmaxf(m_r[r], tm[r]);
      alpha[r] = __expf(m_r[r] - mn);
      m_r[r] = mn;
      rs[r] = 0.f;
    }
#pragma unroll
    for (int n = 0; n < 4; ++n)
#pragma unroll
      for (int r = 0; r < 4; ++r) {
        float ee = __expf(e[n][r] - m_r[r]);  // masked: exp(-huge) -> 0
        e[n][r] = ee;
        rs[r] += ee;
      }
#pragma unroll
    for (int off = 1; off < 16; off <<= 1)
#pragma unroll
      for (int r = 0; r < 4; ++r)
        rs[r] += __shfl_xor(rs[r], off, 64);
#pragma unroll
    for (int r = 0; r < 4; ++r)
      l_r[r] = l_r[r] * alpha[r] + rs[r];
#pragma unroll
    for (int dt = 0; dt < 16; ++dt)
#pragma unroll
      for (int r = 0; r < 4; ++r)
        o_acc[dt][r] *= alpha[r];
    // P: C-layout -> A-layout via LDS (wave-private, pad 72)
    __syncthreads();
#pragma unroll
    for (int n = 0; n < 4; ++n)
#pragma unroll
      for (int r = 0; r < 4; ++r)
        Ps[wave][(quad * 4 + r) * 72 + n * 16 + l16] = f2b(e[n][r]);
    __syncthreads();
    // O += P V : B-operand from Vt (d-major), contiguous keys
#pragma unroll
    for (int ks = 0; ks < 2; ++ks) {
      short8 pa = *(const short8*)(&Ps[wave][l16 * 72 + ks * 32 + quad * 8]);
#pragma unroll
      for (int dt = 0; dt < 16; ++dt) {
        short8 vb = *(const short8*)(Vbase + (size_t)(dt * 16 + l16) * S_ + k0 + ks * 32 + quad * 8);
        o_acc[dt] = __builtin_amdgcn_mfma_f32_16x16x32_bf16(pa, vb, o_acc[dt], 0, 0, 0);
      }
    }
  }
#pragma unroll
  for (int r = 0; r < 4; ++r) l_r[r] = 1.0f / l_r[r];
#pragma unroll
  for (int dt = 0; dt < 16; ++dt)
#pragma unroll
    for (int r = 0; r < 4; ++r) {
      int row = b * S_ + q0 + wave * 16 + quad * 4 + r;
      int col = h * D_ + dt * 16 + l16;
      Ao[(size_t)row * AON_ + col] = f2b(o_acc[dt][r] * l_r[r]);
    }
}

extern "C" void kernel_launch(void* const* d_in, const int* in_sizes, int n_in,
                              void* d_out, int out_size, void* d_ws, size_t ws_size,
                              hipStream_t stream) {
  const float* hidden = (const float*)d_in[0];
  const float* cosp = (const float*)d_in[1];
  const float* sinp = (const float*)d_in[2];
  // d_in[3] = attention_mask: exactly causal 0/-1e9 -> handled analytically
  const float* Wq = (const float*)d_in[4];
  const float* Wk = (const float*)d_in[5];
  const float* Wv = (const float*)d_in[6];
  const float* Wo = (const float*)d_in[7];

  u16* hs  = (u16*)d_ws;                              // 4096 x 2304
  u16* WT  = hs  + (size_t)4096 * HID_;               // 4096 x 2304  ([Wq|Wk|Wv]^T)
  u16* WoT = WT  + (size_t)4096 * HID_;               // 2304 x 2048
  u16* qkv = WoT + (size_t)HID_ * AON_;               // 4096 x 4096
  u16* Qr  = qkv + (size_t)4096 * QKVN_;              // B,H,S,D
  u16* Kr  = Qr  + (size_t)B_ * H_ * S_ * D_;         // B,KVH,S,D
  u16* Vt  = Kr  + (size_t)B_ * KVH_ * S_ * D_;       // B,KVH,D,S
  u16* Ao  = Vt  + (size_t)B_ * KVH_ * S_ * D_;       // 4096 x 2048

  cast_kernel<<<9216, 256, 0, stream>>>(hidden, hs);
  transpose_cast<<<dim3(32, 36), 256, 0, stream>>>(Wq, WT, HID_, 2048);
  transpose_cast<<<dim3(16, 36), 256, 0, stream>>>(Wk, WT + (size_t)2048 * HID_, HID_, 1024);
  transpose_cast<<<dim3(16, 36), 256, 0, stream>>>(Wv, WT + (size_t)3072 * HID_, HID_, 1024);
  transpose_cast<<<dim3(36, 32), 256, 0, stream>>>(Wo, WoT, 2048, HID_);
  gemm_bt<0><<<dim3(32, 32), 256, 0, stream>>>(hs, WT, qkv, 4096, QKVN_, HID_);
  rope_kernel<<<4096, 256, 0, stream>>>(qkv, cosp, sinp, Qr, Kr);
  transpose_v<<<dim3(4, 32, 8), 256, 0, stream>>>(qkv, Vt);
  attn_kernel<<<dim3(32, 8, 2), 256, 0, stream>>>(Qr, Kr, Vt, Ao);
  gemm_bt<1><<<dim3(18, 32), 256, 0, stream>>>(Ao, WoT, d_out, 4096, HID_, 2048);
}

// Round 2
// 478.325 us; speedup vs baseline: 1.8565x; 1.8565x over previous
//
#include <hip/hip_runtime.h>

typedef unsigned short u16;
typedef __attribute__((ext_vector_type(8))) short short8;
typedef __attribute__((ext_vector_type(4))) float f32x4;

constexpr int B_ = 2;
constexpr int H_ = 8;
constexpr int KVH_ = 4;
constexpr int S_ = 2048;
constexpr int D_ = 256;
constexpr int HID_ = 2304;
constexpr int QKVN_ = 4096;   // 2048 q + 1024 k + 1024 v
constexpr int AON_ = 2048;    // H_*D_

__device__ __forceinline__ float b2f(u16 u) {
  union { float f; unsigned int i; } x; x.i = ((unsigned int)u) << 16; return x.f;
}
__device__ __forceinline__ u16 f2b(float f) {
  unsigned int x = __float_as_uint(f);
  unsigned int r = (x + 0x7fffu + ((x >> 16) & 1u)) >> 16;
  return (u16)r;
}

// ---------------- cast fp32 -> bf16 (vectorized) ----------------
__global__ void cast_kernel(const float* __restrict__ in, u16* __restrict__ out) {
  size_t i = ((size_t)blockIdx.x * 256 + threadIdx.x) * 4;
  float4 v = *(const float4*)(in + i);
  unsigned int lo = (unsigned int)f2b(v.x) | ((unsigned int)f2b(v.y) << 16);
  unsigned int hi = (unsigned int)f2b(v.z) | ((unsigned int)f2b(v.w) << 16);
  uint2 o; o.x = lo; o.y = hi;
  *(uint2*)(out + i) = o;
}

// ---------------- transpose + cast: src (R x C) fp32 -> dst (C x R) bf16 ----------------
__global__ void transpose_cast(const float* __restrict__ src, u16* __restrict__ dst,
                               int R, int C) {
  __shared__ float tile[64][65];
  int r0 = blockIdx.y * 64, c0 = blockIdx.x * 64;
  int t = threadIdx.x;
#pragma unroll
  for (int i = 0; i < 16; ++i) {
    int e = i * 256 + t;
    int r = e >> 6, c = e & 63;
    tile[r][c] = src[(size_t)(r0 + r) * C + (c0 + c)];
  }
  __syncthreads();
#pragma unroll
  for (int i = 0; i < 16; ++i) {
    int e = i * 256 + t;
    int orow = e >> 6, ocol = e & 63;
    dst[(size_t)(c0 + orow) * R + (r0 + ocol)] = f2b(tile[ocol][orow]);
  }
}

// ---------------- m97-style bf16 GEMM: C = A(MxK) * B^T where B is (N x K) ----------------
template <int OUTF32>
__global__ __launch_bounds__(256, 2) void gemm_bt(
    const u16* __restrict__ A, const u16* __restrict__ B, void* __restrict__ Cp,
    int M, int N, int K) {
  __shared__ u16 As[128 * 32];
  __shared__ u16 Bs[128 * 32];
  int m0 = blockIdx.y * 128, n0 = blockIdx.x * 128;
  int tid = threadIdx.x;
  int lane = tid & 63, wave = tid >> 6;
  int wy = wave >> 1, wx = wave & 1;
  int quad = lane >> 4, l16 = lane & 15;
  f32x4 acc[4][4] = {};
  for (int k0 = 0; k0 < K; k0 += 32) {
#pragma unroll
    for (int i = 0; i < 2; ++i) {
      int chunk = i * 256 + tid;
      int row = chunk >> 2, col = (chunk & 3) << 3;
      __builtin_amdgcn_global_load_lds(
          (const __attribute__((address_space(1))) void*)(A + (size_t)(m0 + row) * K + k0 + col),
          (__attribute__((address_space(3))) void*)(As + chunk * 8), 16, 0, 0);
    }
#pragma unroll
    for (int i = 0; i < 2; ++i) {
      int chunk = i * 256 + tid;
      int row = chunk >> 2, col = (chunk & 3) << 3;
      __builtin_amdgcn_global_load_lds(
          (const __attribute__((address_space(1))) void*)(B + (size_t)(n0 + row) * K + k0 + col),
          (__attribute__((address_space(3))) void*)(Bs + chunk * 8), 16, 0, 0);
    }
    __syncthreads();
    short8 af[4], bf[4];
#pragma unroll
    for (int mi = 0; mi < 4; ++mi)
      af[mi] = *(const short8*)(As + (wy * 64 + mi * 16 + l16) * 32 + quad * 8);
#pragma unroll
    for (int ni = 0; ni < 4; ++ni)
      bf[ni] = *(const short8*)(Bs + (wx * 64 + ni * 16 + l16) * 32 + quad * 8);
#pragma unroll
    for (int mi = 0; mi < 4; ++mi)
#pragma unroll
      for (int ni = 0; ni < 4; ++ni)
        acc[mi][ni] = __builtin_amdgcn_mfma_f32_16x16x32_bf16(af[mi], bf[ni], acc[mi][ni], 0, 0, 0);
    __syncthreads();
  }
#pragma unroll
  for (int mi = 0; mi < 4; ++mi) {
#pragma unroll
    for (int ni = 0; ni < 4; ++ni) {
#pragma unroll
      for (int r = 0; r < 4; ++r) {
        int row = m0 + wy * 64 + mi * 16 + quad * 4 + r;
        int col = n0 + wx * 64 + ni * 16 + l16;
        if (OUTF32)
          ((float*)Cp)[(size_t)row * N + col] = acc[mi][ni][r];
        else
          ((u16*)Cp)[(size_t)row * N + col] = f2b(acc[mi][ni][r]);
      }
    }
  }
}

// ---------------- RoPE + rearrange: qkv (4096 x 4096) -> Q (B,H,S,D), K (B,KVH,S,D) ----------------
__global__ void rope_kernel(const u16* __restrict__ qkv, const float* __restrict__ cs,
                            const float* __restrict__ sn, u16* __restrict__ Qr,
                            u16* __restrict__ Kr) {
  int row = blockIdx.x;          // b*S + s
  int b = row >> 11, s = row & 2047;
  int d = threadIdx.x;           // 0..255
  const u16* qrow = qkv + (size_t)row * QKVN_;
  float c = cs[(size_t)row * D_ + d];
  float si = sn[(size_t)row * D_ + d];
  int dp = (d < 128) ? d + 128 : d - 128;
  float sgn = (d < 128) ? -1.f : 1.f;
#pragma unroll
  for (int h = 0; h < H_; ++h) {
    float v = b2f(qrow[h * D_ + d]);
    float p = sgn * b2f(qrow[h * D_ + dp]);
    Qr[((size_t)(b * H_ + h) * S_ + s) * D_ + d] = f2b(v * c + p * si);
  }
#pragma unroll
  for (int g = 0; g < KVH_; ++g) {
    float v = b2f(qrow[2048 + g * D_ + d]);
    float p = sgn * b2f(qrow[2048 + g * D_ + dp]);
    Kr[((size_t)(b * KVH_ + g) * S_ + s) * D_ + d] = f2b(v * c + p * si);
  }
}

// ---------------- V transpose: qkv v-part -> Vt (B,KVH,D,S) ----------------
__global__ void transpose_v(const u16* __restrict__ qkv, u16* __restrict__ Vt) {
  __shared__ u16 tile[64][72];
  int d0 = blockIdx.x * 64, s0 = blockIdx.y * 64, g = blockIdx.z; // g = b*KVH+kvh
  int b = g >> 2, kvh = g & 3;
  int t = threadIdx.x;
#pragma unroll
  for (int i = 0; i < 16; ++i) {
    int e = i * 256 + t;
    int r = e >> 6, c = e & 63;
    tile[r][c] = qkv[(size_t)(b * S_ + s0 + r) * QKVN_ + 3072 + kvh * D_ + d0 + c];
  }
  __syncthreads();
#pragma unroll
  for (int i = 0; i < 16; ++i) {
    int e = i * 256 + t;
    int orow = e >> 6, ocol = e & 63;
    Vt[((size_t)g * D_ + d0 + orow) * S_ + s0 + ocol] = tile[ocol][orow];
  }
}

// ---------------- flash attention v2: LDS-staged K/V, fixed-max softmax ----------------
// grid (32 qt, 8 h, 2 b); block 256 = 4 waves, each wave owns 16 q rows of a 64-row tile.
// 32-key kt tiles. K LDS rows XOR-swizzled (chunk ^= key&7); V LDS rows XOR-swizzled
// (chunk ^= d&3) via permuted GLOBAL source (LDS dest of global_load_lds must stay
// lane-linear). Softcap bounds scores at +50 -> fixed softmax max of 50 (no running
// max / alpha rescale; worst-case exponent ~e^-54, safely above fp32 denormals).
__global__ __launch_bounds__(256, 2) void attn_kernel(
    const u16* __restrict__ Qr, const u16* __restrict__ Kr, const u16* __restrict__ Vt,
    u16* __restrict__ Ao) {
  __shared__ u16 Ks[32 * 256];   // 16 KB: 32 keys x 256 d, chunk-swizzled
  __shared__ u16 Vs[256 * 32];   // 16 KB: 256 d x 32 keys, chunk-swizzled
  __shared__ u16 Ps[4][16 * 40]; // 5 KB: wave-private P relayout scratch
  int qt = 31 - blockIdx.x;      // heavy tiles dispatch first (causal balance)
  int h = blockIdx.y, b = blockIdx.z;
  int kvh = h >> 1;  // N_REP = 2
  int tid = threadIdx.x, wave = tid >> 6, lane = tid & 63;
  int quad = lane >> 4, l16 = lane & 15;
  int q0 = qt * 64;
  // Q fragments in registers: wave owns q rows [q0+wave*16, +16); A-layout m=l16, k=quad*8+j
  const u16* Qbase = Qr + ((size_t)(b * H_ + h) * S_ + q0 + wave * 16 + l16) * D_;
  short8 qf[8];
#pragma unroll
  for (int kk = 0; kk < 8; ++kk)
    qf[kk] = *(const short8*)(Qbase + kk * 32 + quad * 8);
  const u16* Kbase = Kr + (size_t)(b * KVH_ + kvh) * S_ * D_;
  const u16* Vbase = Vt + (size_t)(b * KVH_ + kvh) * D_ * S_;
  float l_r[4] = {0.f, 0.f, 0.f, 0.f};
  f32x4 o_acc[16] = {};
  int nkt = 2 * qt + 2;  // 32-key tiles
  for (int kt = 0; kt < nkt; ++kt) {
    int k0 = kt * 32;
    __syncthreads();  // all waves done reading prev K/V tile
    // stage K tile: 16 KB, 4 chunks/thread, chunk-swizzled source
#pragma unroll
    for (int i = 0; i < 4; ++i) {
      int p = i * 256 + tid;
      int s = p >> 5, pc = p & 31;
      int c = pc ^ (s & 7);
      __builtin_amdgcn_global_load_lds(
          (const __attribute__((address_space(1))) void*)(Kbase + (size_t)(k0 + s) * D_ + c * 8),
          (__attribute__((address_space(3))) void*)(Ks + p * 8), 16, 0, 0);
    }
    // stage V tile: 16 KB (rows of 32 keys), chunk-swizzled source
#pragma unroll
    for (int i = 0; i < 4; ++i) {
      int p = i * 256 + tid;
      int d = p >> 2, ps = p & 3;
      int sl = ps ^ (d & 3);
      __builtin_amdgcn_global_load_lds(
          (const __attribute__((address_space(1))) void*)(Vbase + (size_t)d * S_ + k0 + sl * 8),
          (__attribute__((address_space(3))) void*)(Vs + p * 8), 16, 0, 0);
    }
    __syncthreads();  // staged (compiler inserts vmcnt(0) before barrier)
    // S = Q K^T : 2 key sub-tiles of 16
    f32x4 sacc[2] = {};
#pragma unroll
    for (int n = 0; n < 2; ++n) {
      int srow = n * 16 + l16;
      const u16* kb = Ks + srow * 256;
      int sw = l16 & 7;
#pragma unroll
      for (int kk = 0; kk < 8; ++kk) {
        int phys = (kk * 4 + quad) ^ sw;
        short8 bfr = *(const short8*)(kb + phys * 8);
        sacc[n] = __builtin_amdgcn_mfma_f32_16x16x32_bf16(qf[kk], bfr, sacc[n], 0, 0, 0);
      }
    }
    // softcap + causal mask + exp(s - 50), fixed max
    float e[2][4], rs[4];
#pragma unroll
    for (int r = 0; r < 4; ++r) rs[r] = 0.f;
#pragma unroll
    for (int n = 0; n < 2; ++n) {
      int key = k0 + n * 16 + l16;
#pragma unroll
      for (int r = 0; r < 4; ++r) {
        int qq = q0 + wave * 16 + quad * 4 + r;
        // 50*tanh(x/50), x = sacc/16:  t = 50*(E-1)/(E+1), E = exp(2x/50)
        float x2 = sacc[n][r] * (2.0f * 0.0625f / 50.0f);
        x2 = fminf(fmaxf(x2, -30.f), 30.f);
        float E = __expf(x2);
        float s = 50.0f * (E - 1.0f) * __frcp_rn(E + 1.0f);
        s = (key <= qq) ? s : -1e30f;
        float ee = __expf(s - 50.0f);
        e[n][r] = ee;
        rs[r] += ee;
      }
    }
#pragma unroll
    for (int off = 1; off < 16; off <<= 1)
#pragma unroll
      for (int r = 0; r < 4; ++r)
        rs[r] += __shfl_xor(rs[r], off, 64);
#pragma unroll
    for (int r = 0; r < 4; ++r) l_r[r] += rs[r];
    // P: C-layout -> A-layout via wave-private LDS (no barrier needed)
#pragma unroll
    for (int n = 0; n < 2; ++n)
#pragma unroll
      for (int r = 0; r < 4; ++r)
        Ps[wave][(quad * 4 + r) * 40 + n * 16 + l16] = f2b(e[n][r]);
    // O += P V
    short8 pa = *(const short8*)(&Ps[wave][l16 * 40 + quad * 8]);
#pragma unroll
    for (int dt = 0; dt < 16; ++dt) {
      int d = dt * 16 + l16;
      int phys = quad ^ (d & 3);
      short8 vb = *(const short8*)(Vs + d * 32 + phys * 8);
      o_acc[dt] = __builtin_amdgcn_mfma_f32_16x16x32_bf16(pa, vb, o_acc[dt], 0, 0, 0);
    }
  }
#pragma unroll
  for (int r = 0; r < 4; ++r) l_r[r] = 1.0f / l_r[r];
#pragma unroll
  for (int dt = 0; dt < 16; ++dt)
#pragma unroll
    for (int r = 0; r < 4; ++r) {
      int row = b * S_ + q0 + wave * 16 + quad * 4 + r;
      int col = h * D_ + dt * 16 + l16;
      Ao[(size_t)row * AON_ + col] = f2b(o_acc[dt][r] * l_r[r]);
    }
}

extern "C" void kernel_launch(void* const* d_in, const int* in_sizes, int n_in,
                              void* d_out, int out_size, void* d_ws, size_t ws_size,
                              hipStream_t stream) {
  const float* hidden = (const float*)d_in[0];
  const float* cosp = (const float*)d_in[1];
  const float* sinp = (const float*)d_in[2];
  // d_in[3] = attention_mask: exactly causal 0/-1e9 -> handled analytically
  const float* Wq = (const float*)d_in[4];
  const float* Wk = (const float*)d_in[5];
  const float* Wv = (const float*)d_in[6];
  const float* Wo = (const float*)d_in[7];

  u16* hs  = (u16*)d_ws;                              // 4096 x 2304
  u16* WT  = hs  + (size_t)4096 * HID_;               // 4096 x 2304  ([Wq|Wk|Wv]^T)
  u16* WoT = WT  + (size_t)4096 * HID_;               // 2304 x 2048
  u16* qkv = WoT + (size_t)HID_ * AON_;               // 4096 x 4096
  u16* Qr  = qkv + (size_t)4096 * QKVN_;              // B,H,S,D
  u16* Kr  = Qr  + (size_t)B_ * H_ * S_ * D_;         // B,KVH,S,D
  u16* Vt  = Kr  + (size_t)B_ * KVH_ * S_ * D_;       // B,KVH,D,S
  u16* Ao  = Vt  + (size_t)B_ * KVH_ * S_ * D_;       // 4096 x 2048

  cast_kernel<<<9216, 256, 0, stream>>>(hidden, hs);
  transpose_cast<<<dim3(32, 36), 256, 0, stream>>>(Wq, WT, HID_, 2048);
  transpose_cast<<<dim3(16, 36), 256, 0, stream>>>(Wk, WT + (size_t)2048 * HID_, HID_, 1024);
  transpose_cast<<<dim3(16, 36), 256, 0, stream>>>(Wv, WT + (size_t)3072 * HID_, HID_, 1024);
  transpose_cast<<<dim3(36, 32), 256, 0, stream>>>(Wo, WoT, 2048, HID_);
  gemm_bt<0><<<dim3(32, 32), 256, 0, stream>>>(hs, WT, qkv, 4096, QKVN_, HID_);
  rope_kernel<<<4096, 256, 0, stream>>>(qkv, cosp, sinp, Qr, Kr);
  transpose_v<<<dim3(4, 32, 8), 256, 0, stream>>>(qkv, Vt);
  attn_kernel<<<dim3(32, 8, 2), 256, 0, stream>>>(Qr, Kr, Vt, Ao);
  gemm_bt<1><<<dim3(18, 32), 256, 0, stream>>>(Ao, WoT, d_out, 4096, HID_, 2048);
}